// Round 5
// baseline (139.857 us; speedup 1.0000x reference)
//
#include <hip/hip_runtime.h>
#include <hip/hip_bf16.h>

// VectorQuantizer: x [32768 x 64] fp32, e [64 x 1024] fp32.
// d_out = [out (2097152 f32) = x + (q-x), loss = 1.25*mean((q-x)^2)].
//
// R5: two dispatches. vq_prep builds se / eT / bf16 hi-lo splits. vq_main:
// block owns 64 rows, wave owns a 256-code K-slice, ring-4 register prefetch,
// 6-MFMA bf16x3-split scoring, LDS candidate exchange, per-row argmin+gap.
// Ambiguous rows (gap < MARGIN) are exactly re-scored IN-BLOCK (fp32,
// R1-validated ascending-fmaf math) BEFORE the epilogue — latency hidden by
// the other blocks' TLP. Loss scalar finalized by atomic-ticket last block.

#define NROWS 32768
#define DDIM  64
#define KCODE 1024
#define NELEM (NROWS * DDIM)
#define MARGIN 2.5e-4f
#define NBLK (NROWS / 64)

typedef __attribute__((ext_vector_type(8))) short bf16x8;
typedef __attribute__((ext_vector_type(4))) float f32x4;

static __device__ __forceinline__ unsigned short f2bf(float v) {
    __hip_bfloat16 h = __float2bfloat16(v);
    unsigned short b;
    __builtin_memcpy(&b, &h, 2);
    return b;
}
static __device__ __forceinline__ float bf2f(unsigned short b) {
    unsigned int u = ((unsigned int)b) << 16;
    float f;
    __builtin_memcpy(&f, &u, 4);
    return f;
}

// ---------------------------------------------------------------------------
// prep (64 blocks x 256): per block 16 codes. se[k] exact fp32 (ascending-d
// fmaf — must match recheck), eT[k][d] fp32, ehT/elT[k][d] bf16 hi/lo.
__global__ void vq_prep(const float* __restrict__ e,
                        float* __restrict__ se,
                        float* __restrict__ eT,
                        unsigned short* __restrict__ ehT,
                        unsigned short* __restrict__ elT,
                        int* __restrict__ ctrl) {
    __shared__ float tile[64][17];
    const int t = threadIdx.x;
    const int k0 = blockIdx.x * 16;
    if (blockIdx.x == 0 && t < 4) ctrl[t] = 0;
    #pragma unroll
    for (int i = 0; i < 4; ++i) {
        int idx = i * 256 + t;
        int d = idx >> 4, kk = idx & 15;
        tile[d][kk] = e[d * KCODE + k0 + kk];
    }
    __syncthreads();
    if (t < 16) {
        float s = 0.f;
        #pragma unroll
        for (int d = 0; d < 64; ++d) { float v = tile[d][t]; s = fmaf(v, v, s); }
        se[k0 + t] = s;
    }
    const int kk = t >> 4;           // code 0..15
    const int dg = (t & 15) * 4;     // dim chunk
    float v0 = tile[dg + 0][kk], v1 = tile[dg + 1][kk];
    float v2 = tile[dg + 2][kk], v3 = tile[dg + 3][kk];
    *(float4*)&eT[(size_t)(k0 + kk) * 64 + dg] = make_float4(v0, v1, v2, v3);
    unsigned short h0 = f2bf(v0), h1 = f2bf(v1), h2 = f2bf(v2), h3 = f2bf(v3);
    *(ushort4*)&ehT[(size_t)(k0 + kk) * 64 + dg] = make_ushort4(h0, h1, h2, h3);
    *(ushort4*)&elT[(size_t)(k0 + kk) * 64 + dg] =
        make_ushort4(f2bf(v0 - bf2f(h0)), f2bf(v1 - bf2f(h1)),
                     f2bf(v2 - bf2f(h2)), f2bf(v3 - bf2f(h3)));
}

// ---------------------------------------------------------------------------
__launch_bounds__(256, 2)
__global__ void vq_main(const float* __restrict__ x,
                        const float* __restrict__ se,
                        const float* __restrict__ eT,
                        const unsigned short* __restrict__ ehT,
                        const unsigned short* __restrict__ elT,
                        float* __restrict__ out,
                        float* __restrict__ lossAcc,
                        int* __restrict__ done) {
    __shared__ float Lb [64][65];
    __shared__ float Lb2[64][65];
    __shared__ int   Li [64][65];
    __shared__ int   rowIdx[64];
    __shared__ int   flagRows[64];
    __shared__ int   nFlag;
    __shared__ float xs[64];
    __shared__ float wsum[4];

    const int t = threadIdx.x;
    const int lane = t & 63;
    const int w = t >> 6;                 // 0..3, this wave's K-slice
    const int quad = lane >> 4, l15 = lane & 15;
    const int rowBlk = blockIdx.x * 64;

    if (t == 0) nFlag = 0;

    // ---- A fragments: 4 M-tiles (rows rowBlk..rowBlk+63), built in-register ----
    bf16x8 ah[4][2], al[4][2];
    #pragma unroll
    for (int mt = 0; mt < 4; ++mt) {
        #pragma unroll
        for (int ks = 0; ks < 2; ++ks) {
            const float4* ap = (const float4*)(x + (size_t)(rowBlk + mt * 16 + l15) * 64
                                               + ks * 32 + quad * 8);
            float4 a0 = ap[0], a1 = ap[1];
            float av[8] = {a0.x, a0.y, a0.z, a0.w, a1.x, a1.y, a1.z, a1.w};
            bf16x8 h, l;
            #pragma unroll
            for (int j = 0; j < 8; ++j) {
                unsigned short hb = f2bf(av[j]);
                h[j] = (short)hb;
                l[j] = (short)f2bf(av[j] - bf2f(hb));
            }
            ah[mt][ks] = h; al[mt][ks] = l;
        }
    }

    float sb[4][4], sb2[4][4];
    int   si[4][4];
    #pragma unroll
    for (int mt = 0; mt < 4; ++mt)
        #pragma unroll
        for (int r = 0; r < 4; ++r) { sb[mt][r] = 3.4e38f; sb2[mt][r] = 3.4e38f; si[mt][r] = 0; }

    // ---- B ring-4 register prefetch over this wave's 256 codes (16 tiles) ----
    const int cbase = w * 256;
    bf16x8 h0[4], h1[4], l0[4], l1[4];
    float sen[4];
    #pragma unroll
    for (int p = 0; p < 4; ++p) {
        const int nl = cbase + p * 16 + l15;
        const bf16x8* hp = (const bf16x8*)(ehT + (size_t)nl * 64 + quad * 8);
        const bf16x8* lp = (const bf16x8*)(elT + (size_t)nl * 64 + quad * 8);
        h0[p] = hp[0]; h1[p] = hp[4]; l0[p] = lp[0]; l1[p] = lp[4];
        sen[p] = se[nl];
    }

    #pragma unroll 4
    for (int nt = 0; nt < 16; ++nt) {
        const int p = nt & 3;
        bf16x8 ch0 = h0[p], ch1 = h1[p], cl0 = l0[p], cl1 = l1[p];
        float cse = sen[p];
        {   // prefetch tile nt+4 (tiles 16..19 read ws pad; never consumed)
            const int nl = cbase + (nt + 4) * 16 + l15;
            const bf16x8* hp = (const bf16x8*)(ehT + (size_t)nl * 64 + quad * 8);
            const bf16x8* lp = (const bf16x8*)(elT + (size_t)nl * 64 + quad * 8);
            h0[p] = hp[0]; h1[p] = hp[4]; l0[p] = lp[0]; l1[p] = lp[4];
            sen[p] = se[nl];
        }
        const int nl = cbase + nt * 16 + l15;
        #pragma unroll
        for (int mt = 0; mt < 4; ++mt) {
            f32x4 aA = {0.f, 0.f, 0.f, 0.f}, aB = {0.f, 0.f, 0.f, 0.f};
            aA = __builtin_amdgcn_mfma_f32_16x16x32_bf16(ah[mt][0], ch0, aA, 0, 0, 0);
            aB = __builtin_amdgcn_mfma_f32_16x16x32_bf16(ah[mt][1], ch1, aB, 0, 0, 0);
            aA = __builtin_amdgcn_mfma_f32_16x16x32_bf16(ah[mt][0], cl0, aA, 0, 0, 0);
            aB = __builtin_amdgcn_mfma_f32_16x16x32_bf16(ah[mt][1], cl1, aB, 0, 0, 0);
            aA = __builtin_amdgcn_mfma_f32_16x16x32_bf16(al[mt][0], ch0, aA, 0, 0, 0);
            aB = __builtin_amdgcn_mfma_f32_16x16x32_bf16(al[mt][1], ch1, aB, 0, 0, 0);
            #pragma unroll
            for (int r = 0; r < 4; ++r) {
                float key = fmaf(-2.f, aA[r] + aB[r], cse);   // se - 2*dot
                bool lt = key < sb[mt][r];                     // strict: earliest k wins
                sb2[mt][r] = fminf(sb2[mt][r], fmaxf(sb[mt][r], key));
                sb[mt][r]  = fminf(sb[mt][r], key);
                si[mt][r]  = lt ? nl : si[mt][r];
            }
        }
    }

    // ---- exchange candidates: row-local = mt*16+quad*4+r, col = w*16+l15 ----
    const int col = w * 16 + l15;
    #pragma unroll
    for (int mt = 0; mt < 4; ++mt)
        #pragma unroll
        for (int r = 0; r < 4; ++r) {
            int rr = mt * 16 + quad * 4 + r;
            Lb [rr][col] = sb [mt][r];
            Lb2[rr][col] = sb2[mt][r];
            Li [rr][col] = si [mt][r];
        }
    __syncthreads();

    // ---- per-row reduce over 64 candidates; flag ambiguous rows ----
    if (t < 64) {
        float B = Lb[t][0], B2 = Lb2[t][0];
        int I = Li[t][0];
        for (int c = 1; c < 64; ++c) {
            float b = Lb[t][c], b2 = Lb2[t][c];
            int i = Li[t][c];
            float nB2 = fminf(fminf(B2, b2), fmaxf(B, b));
            bool take = (b < B) || (b == B && i < I);
            B = take ? b : B;
            I = take ? i : I;
            B2 = nB2;
        }
        rowIdx[t] = I;
        if (B2 - B < MARGIN) {
            int p = atomicAdd(&nFlag, 1);
            flagRows[p] = t;
        }
    }
    __syncthreads();

    // ---- exact fp32 recheck of flagged rows (rare; R1-validated math) ----
    {
        float* cb = &Lb[0][0];    // reuse LDS (Lb/Li dead after reduce)
        int*   ci = &Li[0][0];
        const int nf = nFlag;
        for (int f = 0; f < nf; ++f) {
            const int r = flagRows[f];
            if (t < 64) xs[t] = x[(size_t)(rowBlk + r) * 64 + t];
            __syncthreads();

            float sx = 0.f;
            #pragma unroll
            for (int d = 0; d < 64; ++d) sx = fmaf(xs[d], xs[d], sx);

            float db = 3.4e38f; int di = 0;
            #pragma unroll
            for (int j = 0; j < 4; ++j) {
                int k = t * 4 + j;
                // preload the whole code row (16 independent float4 loads),
                // then the ascending dependent fmaf chain (matches R1 bitwise)
                const float4* ep = (const float4*)(eT + (size_t)k * 64);
                float er[64];
                #pragma unroll
                for (int i = 0; i < 16; ++i) {
                    float4 v = ep[i];
                    er[4*i+0] = v.x; er[4*i+1] = v.y; er[4*i+2] = v.z; er[4*i+3] = v.w;
                }
                float dot = 0.f;
                #pragma unroll
                for (int d = 0; d < 64; ++d) dot = fmaf(xs[d], er[d], dot);
                float t0 = sx + se[k];
                float dd = t0 - 2.0f * dot;
                if (dd < db) { db = dd; di = k; }
            }
            cb[t] = db; ci[t] = di;
            __syncthreads();
            if (t == 0) {
                float B = cb[0]; int I = ci[0];
                for (int c = 1; c < 256; ++c)
                    if (cb[c] < B) { B = cb[c]; I = ci[c]; }   // ascending k
                rowIdx[r] = I;
            }
            __syncthreads();
        }
    }

    // ---- epilogue: wave w writes rows [w*16, w*16+16); lane: row w*16+l15 ----
    {
        const int rl = w * 16 + l15;
        const int idx = rowIdx[rl];
        const float4* qrow = (const float4*)(eT + (size_t)idx * 64 + quad * 16);
        const float4* xrow = (const float4*)(x + (size_t)(rowBlk + rl) * 64 + quad * 16);
        float4* orow = (float4*)(out + (size_t)(rowBlk + rl) * 64 + quad * 16);
        float lsum = 0.f;
        #pragma unroll
        for (int i = 0; i < 4; ++i) {
            float4 q = qrow[i];
            float4 xv = xrow[i];
            float4 o;
            float dx;
            dx = q.x - xv.x; o.x = xv.x + dx; lsum = fmaf(dx, dx, lsum);
            dx = q.y - xv.y; o.y = xv.y + dx; lsum = fmaf(dx, dx, lsum);
            dx = q.z - xv.z; o.z = xv.z + dx; lsum = fmaf(dx, dx, lsum);
            dx = q.w - xv.w; o.w = xv.w + dx; lsum = fmaf(dx, dx, lsum);
            orow[i] = o;
        }
        #pragma unroll
        for (int off = 32; off > 0; off >>= 1)
            lsum += __shfl_down(lsum, off, 64);
        if (lane == 0) wsum[w] = lsum;
    }
    __syncthreads();

    // ---- block loss add, then atomic-ticket finalize by the last block ----
    if (t == 0) {
        atomicAdd(lossAcc, wsum[0] + wsum[1] + wsum[2] + wsum[3]);
        __threadfence();
        int fin = atomicAdd(done, 1);
        if (fin == NBLK - 1) {
            float s = atomicAdd(lossAcc, 0.0f);   // coherent read of final sum
            float m = s / (float)NELEM;
            out[NELEM] = 0.25f * m + m;
        }
    }
}

// ---------------------------------------------------------------------------
extern "C" void kernel_launch(void* const* d_in, const int* in_sizes, int n_in,
                              void* d_out, int out_size, void* d_ws, size_t ws_size,
                              hipStream_t stream) {
    const float* x = (const float*)d_in[0];
    const float* e = (const float*)d_in[1];
    float* out = (float*)d_out;
    float* ws  = (float*)d_ws;

    // ws layout (float offsets):
    //   [0..15]   ctrl: lossAcc, (unused), done, spare
    //   +64       se   [1088 used incl. 64-code read pad; region to +1280]
    //   +1280     eT   [65536]
    //   +66816    ehT  [1088*64 ushort = 34816 f]
    //   +101632   elT  [1088*64 ushort = 34816 f]
    float* lossAcc      = ws;
    int*   done         = (int*)(ws + 2);
    float* se           = ws + 64;
    float* eT           = ws + 1280;
    unsigned short* ehT = (unsigned short*)(ws + 66816);
    unsigned short* elT = (unsigned short*)(ws + 101632);

    vq_prep<<<64, 256, 0, stream>>>(e, se, eT, ehT, elT, (int*)ws);
    vq_main<<<NBLK, 256, 0, stream>>>(x, se, eT, ehT, elT, out, lossAcc, done);
}